// Round 1
// baseline (3447.144 us; speedup 1.0000x reference)
//
#include <hip/hip_runtime.h>
#include <hip/hip_bf16.h>

#define HDIM 50
#define G3   150
#define TSEQ 512
#define BATCH 2048

// Activation buffer layout: act[t][b][i] = t*(BATCH*HDIM) + b*HDIM + i
// Size: 512*2048*50*4 B = 209,715,200 B (lives in d_ws)

template<int IN_DIM, int NB>
__global__ __launch_bounds__(192)
void gru_layer_kernel(const float* __restrict__ xin_g,   // IN_DIM==1: x [B][T]; else act [T][B][H] (in-place ok)
                      float* __restrict__ act,           // out: act [T][B][H]
                      const float* __restrict__ Wih,     // [150][IN_DIM]
                      const float* __restrict__ Whh,     // [150][50]
                      const float* __restrict__ bih,     // [150]
                      const float* __restrict__ bhh)     // [150]
{
    const int tid = threadIdx.x;
    const int b0  = blockIdx.x * NB;

    __shared__ float h_s [NB][56];   // stride 56 floats = 224 B (16B aligned rows)
    __shared__ float x_s [NB][56];
    __shared__ float s_rz[NB][100];  // pre-activations for r (0..49) and z (50..99)
    __shared__ float s_xn[NB][50];   // gx for n-gate
    __shared__ float s_hn[NB][50];   // gh for n-gate

    // ---- load this thread's weight rows into registers (once) ----
    float w_hh[HDIM];
    float w_ih[IN_DIM];
    float b_i = 0.f, b_h = 0.f;
    if (tid < G3) {
#pragma unroll
        for (int j = 0; j < HDIM; ++j) w_hh[j] = Whh[tid*HDIM + j];
#pragma unroll
        for (int j = 0; j < IN_DIM; ++j) w_ih[j] = Wih[tid*IN_DIM + j];
        b_i = bih[tid];
        b_h = bhh[tid];
    }
    // init h = 0
    for (int k = tid; k < NB*HDIM; k += 192) h_s[k/HDIM][k%HDIM] = 0.f;
    __syncthreads();

    for (int t = 0; t < TSEQ; ++t) {
        // ---- stage 1: load x_in(t) into LDS ----
        if (IN_DIM == 1) {
            if (tid < NB) x_s[tid][0] = xin_g[(size_t)(b0 + tid)*TSEQ + t];
        } else {
            for (int k = tid; k < NB*HDIM; k += 192) {
                int b = k / HDIM, j = k % HDIM;
                x_s[b][j] = xin_g[(size_t)t*(BATCH*HDIM) + (size_t)(b0 + b)*HDIM + j];
            }
        }
        __syncthreads();

        // ---- stage 2: gate GEMV (weights in regs, h/x broadcast from LDS) ----
        if (tid < G3) {
#pragma unroll
            for (int b = 0; b < NB; ++b) {
                float gx = b_i;
                if (IN_DIM == 1) {
                    gx += w_ih[0] * x_s[b][0];
                } else {
#pragma unroll
                    for (int j = 0; j < IN_DIM; ++j) gx += w_ih[j] * x_s[b][j];
                }
                float gh = b_h;
#pragma unroll
                for (int j = 0; j < HDIM; ++j) gh += w_hh[j] * h_s[b][j];

                if (tid < 100) {
                    s_rz[b][tid] = gx + gh;
                } else {
                    s_xn[b][tid-100] = gx;
                    s_hn[b][tid-100] = gh;
                }
            }
        }
        __syncthreads();

        // ---- stage 3: elementwise gate update, h write (LDS + global) ----
        if (tid < HDIM) {
#pragma unroll
            for (int b = 0; b < NB; ++b) {
                float r = 1.f / (1.f + __expf(-s_rz[b][tid]));
                float z = 1.f / (1.f + __expf(-s_rz[b][tid+50]));
                float n = tanhf(s_xn[b][tid] + r * s_hn[b][tid]);
                float hn = (1.f - z)*n + z*h_s[b][tid];
                h_s[b][tid] = hn;
                act[(size_t)t*(BATCH*HDIM) + (size_t)(b0 + b)*HDIM + tid] = hn;
            }
        }
        // no barrier needed here: stage-1 barrier of next iter orders h_s
        // writes (stage 3) before h_s reads (stage 2), and the stage-2
        // barrier orders x_s reads before next stage-1 overwrite.
    }
}

__global__ __launch_bounds__(256)
void fc_sigmoid_kernel(const float* __restrict__ act,
                       const float* __restrict__ fcw,  // [1][50]
                       const float* __restrict__ fcb,  // [1]
                       float* __restrict__ out)        // [2048]
{
    int b = blockIdx.x*256 + threadIdx.x;
    if (b >= BATCH) return;
    const float* row = act + (size_t)(TSEQ-1)*(BATCH*HDIM) + (size_t)b*HDIM;
    float s = fcb[0];
#pragma unroll
    for (int j = 0; j < HDIM; ++j) s += row[j]*fcw[j];
    out[b] = 1.f / (1.f + __expf(-s));
}

extern "C" void kernel_launch(void* const* d_in, const int* in_sizes, int n_in,
                              void* d_out, int out_size, void* d_ws, size_t ws_size,
                              hipStream_t stream) {
    const float* x     = (const float*)d_in[0];   // [2048][512][1]
    const float* W_ih0 = (const float*)d_in[1];   // [150][1]
    const float* W_hh0 = (const float*)d_in[2];   // [150][50]
    const float* b_ih0 = (const float*)d_in[3];   // [150]
    const float* b_hh0 = (const float*)d_in[4];   // [150]
    const float* W_ih  = (const float*)d_in[5];   // [3][150][50]
    const float* W_hh  = (const float*)d_in[6];   // [3][150][50]
    const float* b_ih  = (const float*)d_in[7];   // [3][150]
    const float* b_hh  = (const float*)d_in[8];   // [3][150]
    const float* fc_w  = (const float*)d_in[9];   // [1][50]
    const float* fc_b  = (const float*)d_in[10];  // [1]
    float* out = (float*)d_out;

    float* act = (float*)d_ws;                    // [512][2048][50] fp32

    constexpr int NB = 2;
    dim3 grid(BATCH / NB), block(192);

    // layer 0 (input dim 1)
    gru_layer_kernel<1, NB><<<grid, block, 0, stream>>>(x, act, W_ih0, W_hh0, b_ih0, b_hh0);
    // layers 1..3 (input dim 50), in-place on act
    for (int l = 0; l < 3; ++l) {
        gru_layer_kernel<HDIM, NB><<<grid, block, 0, stream>>>(
            act, act,
            W_ih + (size_t)l*G3*HDIM, W_hh + (size_t)l*G3*HDIM,
            b_ih + (size_t)l*G3,      b_hh + (size_t)l*G3);
    }
    // FC + sigmoid
    fc_sigmoid_kernel<<<BATCH/256, 256, 0, stream>>>(act, fc_w, fc_b, out);
}

// Round 2
// 3388.332 us; speedup vs baseline: 1.0174x; 1.0174x over previous
//
#include <hip/hip_runtime.h>
#include <hip/hip_bf16.h>

#define HDIM 50
#define G3   150
#define TSEQ 512
#define BATCH 2048

// act[t][b][i] = t*(BATCH*HDIM) + b*HDIM + i   (209,715,200 B in d_ws)

template<int IN_DIM, int NB>
__global__ __launch_bounds__(192, 3)
void gru_layer_kernel(const float* __restrict__ xin_g,   // IN_DIM==1: x [B][T]; else act [T][B][H] (in-place ok)
                      float* __restrict__ act,           // out: act [T][B][H]
                      const float* __restrict__ Wih,     // [150][IN_DIM]
                      const float* __restrict__ Whh,     // [150][50]
                      const float* __restrict__ bih,     // [150]
                      const float* __restrict__ bhh)     // [150]
{
    const int tid = threadIdx.x;
    const int b0  = blockIdx.x * NB;

    __shared__ __align__(16) float h_s [NB][56];   // rows 16B-aligned (224 B)
    __shared__ __align__(16) float x_s [NB][56];
    __shared__ float s_rz[NB][100];
    __shared__ float s_xn[NB][50];
    __shared__ float s_hn[NB][50];
    // layer-0 only: whole x rows resident in LDS (4 KB)
    __shared__ float x_row[(IN_DIM==1) ? NB : 1][(IN_DIM==1) ? TSEQ : 1];

    // ---- one-time: weight rows -> registers (padded to 52 with zeros) ----
    float w_hh[52];
    float w_ih[(IN_DIM==1) ? 1 : 52];
    float b_i = 0.f, b_h = 0.f;
    if (tid < G3) {
#pragma unroll
        for (int j = 0; j < HDIM; ++j) w_hh[j] = Whh[tid*HDIM + j];
        w_hh[50] = 0.f; w_hh[51] = 0.f;
        if (IN_DIM == 1) {
            w_ih[0] = Wih[tid];
        } else {
#pragma unroll
            for (int j = 0; j < IN_DIM; ++j) w_ih[j] = Wih[tid*IN_DIM + j];
            w_ih[50] = 0.f; w_ih[51] = 0.f;
        }
        b_i = bih[tid];
        b_h = bhh[tid];
    }
    // init h=0 and zero the float4 padding tails
    for (int k = tid; k < NB*56; k += 192) h_s[k/56][k%56] = 0.f;
    for (int k = tid; k < NB*56; k += 192) x_s[k/56][k%56] = 0.f;

    if (IN_DIM == 1) {
        // preload full x rows for this block's batches (coalesced)
        for (int k = tid; k < NB*TSEQ; k += 192)
            x_row[k/TSEQ][k%TSEQ] = xin_g[(size_t)(b0 + k/TSEQ)*TSEQ + (k%TSEQ)];
    }

    // prefetch x(t=0) into registers (IN_DIM==50 path)
    float xpre = 0.f;
    if (IN_DIM != 1 && tid < NB*HDIM) {
        xpre = xin_g[(size_t)(b0 + tid/HDIM)*HDIM + (tid%HDIM)];  // t=0 term
    }
    __syncthreads();

    for (int t = 0; t < TSEQ; ++t) {
        // ---- stage 1: publish x(t) to LDS; prefetch x(t+1) ----
        if (IN_DIM != 1) {
            if (tid < NB*HDIM) x_s[tid/HDIM][tid%HDIM] = xpre;
        }
        __syncthreads();
        if (IN_DIM != 1 && tid < NB*HDIM && t+1 < TSEQ) {
            xpre = xin_g[(size_t)(t+1)*(BATCH*HDIM) + (size_t)(b0 + tid/HDIM)*HDIM + (tid%HDIM)];
        }

        // ---- stage 2: gate GEMV (weights in regs, float4 LDS broadcasts) ----
        if (tid < G3) {
#pragma unroll
            for (int b = 0; b < NB; ++b) {
                float gx = b_i;
                if (IN_DIM == 1) {
                    gx = fmaf(w_ih[0], x_row[b][t], gx);
                } else {
                    const float4* x4 = (const float4*)&x_s[b][0];
#pragma unroll
                    for (int q = 0; q < 13; ++q) {
                        float4 v = x4[q];
                        gx = fmaf(w_ih[4*q+0], v.x, gx);
                        gx = fmaf(w_ih[4*q+1], v.y, gx);
                        gx = fmaf(w_ih[4*q+2], v.z, gx);
                        gx = fmaf(w_ih[4*q+3], v.w, gx);
                    }
                }
                float gh = b_h;
                const float4* h4 = (const float4*)&h_s[b][0];
#pragma unroll
                for (int q = 0; q < 13; ++q) {
                    float4 v = h4[q];
                    gh = fmaf(w_hh[4*q+0], v.x, gh);
                    gh = fmaf(w_hh[4*q+1], v.y, gh);
                    gh = fmaf(w_hh[4*q+2], v.z, gh);
                    gh = fmaf(w_hh[4*q+3], v.w, gh);
                }
                if (tid < 100) {
                    s_rz[b][tid] = gx + gh;
                } else {
                    s_xn[b][tid-100] = gx;
                    s_hn[b][tid-100] = gh;
                }
            }
        }
        __syncthreads();

        // ---- stage 3: gate update over NB*50 threads ----
        if (tid < NB*HDIM) {
            const int b = tid / HDIM, u = tid % HDIM;
            float r = 1.f / (1.f + __expf(-s_rz[b][u]));
            float z = 1.f / (1.f + __expf(-s_rz[b][u+50]));
            float n = tanhf(s_xn[b][u] + r * s_hn[b][u]);
            float hn = (1.f - z)*n + z*h_s[b][u];
            h_s[b][u] = hn;
            act[(size_t)t*(BATCH*HDIM) + (size_t)(b0 + b)*HDIM + u] = hn;
        }
        // next loop-top barrier orders stage-3 h_s/x_s hazards
    }
}

__global__ __launch_bounds__(256)
void fc_sigmoid_kernel(const float* __restrict__ act,
                       const float* __restrict__ fcw,
                       const float* __restrict__ fcb,
                       float* __restrict__ out)
{
    int b = blockIdx.x*256 + threadIdx.x;
    if (b >= BATCH) return;
    const float* row = act + (size_t)(TSEQ-1)*(BATCH*HDIM) + (size_t)b*HDIM;
    float s = fcb[0];
#pragma unroll
    for (int j = 0; j < HDIM; ++j) s = fmaf(row[j], fcw[j], s);
    out[b] = 1.f / (1.f + __expf(-s));
}

extern "C" void kernel_launch(void* const* d_in, const int* in_sizes, int n_in,
                              void* d_out, int out_size, void* d_ws, size_t ws_size,
                              hipStream_t stream) {
    const float* x     = (const float*)d_in[0];
    const float* W_ih0 = (const float*)d_in[1];
    const float* W_hh0 = (const float*)d_in[2];
    const float* b_ih0 = (const float*)d_in[3];
    const float* b_hh0 = (const float*)d_in[4];
    const float* W_ih  = (const float*)d_in[5];
    const float* W_hh  = (const float*)d_in[6];
    const float* b_ih  = (const float*)d_in[7];
    const float* b_hh  = (const float*)d_in[8];
    const float* fc_w  = (const float*)d_in[9];
    const float* fc_b  = (const float*)d_in[10];
    float* out = (float*)d_out;

    float* act = (float*)d_ws;   // [512][2048][50] fp32

    constexpr int NB = 2;
    dim3 grid(BATCH / NB), block(192);

    gru_layer_kernel<1, NB><<<grid, block, 0, stream>>>(x, act, W_ih0, W_hh0, b_ih0, b_hh0);
    for (int l = 0; l < 3; ++l) {
        gru_layer_kernel<HDIM, NB><<<grid, block, 0, stream>>>(
            act, act,
            W_ih + (size_t)l*G3*HDIM, W_hh + (size_t)l*G3*HDIM,
            b_ih + (size_t)l*G3,      b_hh + (size_t)l*G3);
    }
    fc_sigmoid_kernel<<<BATCH/256, 256, 0, stream>>>(act, fc_w, fc_b, out);
}

// Round 4
// 2995.913 us; speedup vs baseline: 1.1506x; 1.1310x over previous
//
#include <hip/hip_runtime.h>
#include <hip/hip_bf16.h>

#define HDIM 50
#define G3   150
#define TSEQ 512
#define BATCH 2048

// act[t][b][i] = t*(BATCH*HDIM) + b*HDIM + i   (209,715,200 B in d_ws)

// 13 named float4 weight regs per matrix (52 floats, last 2 zero-padded).
// NOTE: member access must be written "p##0 .x" (space!) — "p##0.x" lexes
// "0.x" as one pp-number and the paste forms an invalid token.
#define W_DECL(p) float4 p##0,p##1,p##2,p##3,p##4,p##5,p##6,p##7,p##8,p##9,p##10,p##11,p##12
#define W_LOAD(p, base)  do { \
    const float* _w = (base); \
    p##0  = make_float4(_w[ 0],_w[ 1],_w[ 2],_w[ 3]); \
    p##1  = make_float4(_w[ 4],_w[ 5],_w[ 6],_w[ 7]); \
    p##2  = make_float4(_w[ 8],_w[ 9],_w[10],_w[11]); \
    p##3  = make_float4(_w[12],_w[13],_w[14],_w[15]); \
    p##4  = make_float4(_w[16],_w[17],_w[18],_w[19]); \
    p##5  = make_float4(_w[20],_w[21],_w[22],_w[23]); \
    p##6  = make_float4(_w[24],_w[25],_w[26],_w[27]); \
    p##7  = make_float4(_w[28],_w[29],_w[30],_w[31]); \
    p##8  = make_float4(_w[32],_w[33],_w[34],_w[35]); \
    p##9  = make_float4(_w[36],_w[37],_w[38],_w[39]); \
    p##10 = make_float4(_w[40],_w[41],_w[42],_w[43]); \
    p##11 = make_float4(_w[44],_w[45],_w[46],_w[47]); \
    p##12 = make_float4(_w[48],_w[49],0.f,0.f); \
} while(0)
#define W_DOT4(acc, p, q, _t) \
    acc=fmaf(p##q .x,_t.x,acc); acc=fmaf(p##q .y,_t.y,acc); \
    acc=fmaf(p##q .z,_t.z,acc); acc=fmaf(p##q .w,_t.w,acc);
// acc += dot(p, v4[0..12]) with v4 = float4* into LDS (broadcast reads)
#define W_DOT(acc, p, v4) do { \
    float4 _t; \
    _t=(v4)[ 0]; W_DOT4(acc, p, 0, _t) \
    _t=(v4)[ 1]; W_DOT4(acc, p, 1, _t) \
    _t=(v4)[ 2]; W_DOT4(acc, p, 2, _t) \
    _t=(v4)[ 3]; W_DOT4(acc, p, 3, _t) \
    _t=(v4)[ 4]; W_DOT4(acc, p, 4, _t) \
    _t=(v4)[ 5]; W_DOT4(acc, p, 5, _t) \
    _t=(v4)[ 6]; W_DOT4(acc, p, 6, _t) \
    _t=(v4)[ 7]; W_DOT4(acc, p, 7, _t) \
    _t=(v4)[ 8]; W_DOT4(acc, p, 8, _t) \
    _t=(v4)[ 9]; W_DOT4(acc, p, 9, _t) \
    _t=(v4)[10]; W_DOT4(acc, p, 10, _t) \
    _t=(v4)[11]; W_DOT4(acc, p, 11, _t) \
    _t=(v4)[12]; acc=fmaf(p##12 .x,_t.x,acc); acc=fmaf(p##12 .y,_t.y,acc); \
} while(0)

template<int IN_DIM, int NB>
__global__ __launch_bounds__(192, 3)
void gru_layer_kernel(const float* __restrict__ xin_g,
                      float* __restrict__ act,
                      const float* __restrict__ Wih,
                      const float* __restrict__ Whh,
                      const float* __restrict__ bih,
                      const float* __restrict__ bhh)
{
    const int tid = threadIdx.x;
    const int b0  = blockIdx.x * NB;
    const int row = (tid < G3) ? tid : (G3 - 1);   // clamped: unconditional init

    __shared__ __align__(16) float h_s [NB][56];
    __shared__ __align__(16) float x_s [NB][56];
    __shared__ float s_rz[NB][100];
    __shared__ float s_xn[NB][50];
    __shared__ float s_hn[NB][50];
    __shared__ float x_row[(IN_DIM==1) ? NB : 1][(IN_DIM==1) ? TSEQ : 1];

    // ---- weights -> named float4 registers (SROA-proof) ----
    W_DECL(wh);
    W_LOAD(wh, Whh + row*HDIM);
    float wi_scalar = 0.f;
    W_DECL(wi);
    if (IN_DIM == 1) {
        wi_scalar = Wih[row];
        wi0=wi1=wi2=wi3=wi4=wi5=wi6=wi7=wi8=wi9=wi10=wi11=wi12=make_float4(0.f,0.f,0.f,0.f);
    } else {
        W_LOAD(wi, Wih + row*IN_DIM);
    }
    const float b_i = bih[row];
    const float b_h = bhh[row];

    for (int k = tid; k < NB*56; k += 192) h_s[k/56][k%56] = 0.f;
    for (int k = tid; k < NB*56; k += 192) x_s[k/56][k%56] = 0.f;

    if (IN_DIM == 1) {
        for (int k = tid; k < NB*TSEQ; k += 192)
            x_row[k/TSEQ][k%TSEQ] = xin_g[(size_t)(b0 + k/TSEQ)*TSEQ + (k%TSEQ)];
    }

    float xpre = 0.f;
    if (IN_DIM != 1 && tid < NB*HDIM) {
        xpre = xin_g[(size_t)(b0 + tid/HDIM)*HDIM + (tid%HDIM)];
    }
    __syncthreads();

    for (int t = 0; t < TSEQ; ++t) {
        // ---- stage 1: publish x(t); prefetch x(t+1) ----
        if (IN_DIM != 1) {
            if (tid < NB*HDIM) x_s[tid/HDIM][tid%HDIM] = xpre;
        }
        __syncthreads();
        if (IN_DIM != 1 && tid < NB*HDIM && t+1 < TSEQ) {
            xpre = xin_g[(size_t)(t+1)*(BATCH*HDIM) + (size_t)(b0 + tid/HDIM)*HDIM + (tid%HDIM)];
        }

        // ---- stage 2: gate GEMV, weights in registers ----
        if (tid < G3) {
#pragma unroll
            for (int b = 0; b < NB; ++b) {
                float gx = b_i;
                if (IN_DIM == 1) {
                    gx = fmaf(wi_scalar, x_row[b][t], gx);
                } else {
                    const float4* x4 = (const float4*)&x_s[b][0];
                    W_DOT(gx, wi, x4);
                }
                float gh = b_h;
                const float4* h4 = (const float4*)&h_s[b][0];
                W_DOT(gh, wh, h4);

                if (tid < 100) {
                    s_rz[b][tid] = gx + gh;
                } else {
                    s_xn[b][tid-100] = gx;
                    s_hn[b][tid-100] = gh;
                }
            }
        }
        __syncthreads();

        // ---- stage 3: gate update ----
        if (tid < NB*HDIM) {
            const int b = tid / HDIM, u = tid % HDIM;
            float r = 1.f / (1.f + __expf(-s_rz[b][u]));
            float z = 1.f / (1.f + __expf(-s_rz[b][u+50]));
            float n = tanhf(s_xn[b][u] + r * s_hn[b][u]);
            float hn = (1.f - z)*n + z*h_s[b][u];
            h_s[b][u] = hn;
            act[(size_t)t*(BATCH*HDIM) + (size_t)(b0 + b)*HDIM + u] = hn;
        }
    }
}

__global__ __launch_bounds__(256)
void fc_sigmoid_kernel(const float* __restrict__ act,
                       const float* __restrict__ fcw,
                       const float* __restrict__ fcb,
                       float* __restrict__ out)
{
    int b = blockIdx.x*256 + threadIdx.x;
    if (b >= BATCH) return;
    const float* row = act + (size_t)(TSEQ-1)*(BATCH*HDIM) + (size_t)b*HDIM;
    float s = fcb[0];
#pragma unroll
    for (int j = 0; j < HDIM; ++j) s = fmaf(row[j], fcw[j], s);
    out[b] = 1.f / (1.f + __expf(-s));
}

extern "C" void kernel_launch(void* const* d_in, const int* in_sizes, int n_in,
                              void* d_out, int out_size, void* d_ws, size_t ws_size,
                              hipStream_t stream) {
    const float* x     = (const float*)d_in[0];
    const float* W_ih0 = (const float*)d_in[1];
    const float* W_hh0 = (const float*)d_in[2];
    const float* b_ih0 = (const float*)d_in[3];
    const float* b_hh0 = (const float*)d_in[4];
    const float* W_ih  = (const float*)d_in[5];
    const float* W_hh  = (const float*)d_in[6];
    const float* b_ih  = (const float*)d_in[7];
    const float* b_hh  = (const float*)d_in[8];
    const float* fc_w  = (const float*)d_in[9];
    const float* fc_b  = (const float*)d_in[10];
    float* out = (float*)d_out;

    float* act = (float*)d_ws;   // [512][2048][50] fp32

    constexpr int NB = 2;
    dim3 grid(BATCH / NB), block(192);

    gru_layer_kernel<1, NB><<<grid, block, 0, stream>>>(x, act, W_ih0, W_hh0, b_ih0, b_hh0);
    for (int l = 0; l < 3; ++l) {
        gru_layer_kernel<HDIM, NB><<<grid, block, 0, stream>>>(
            act, act,
            W_ih + (size_t)l*G3*HDIM, W_hh + (size_t)l*G3*HDIM,
            b_ih + (size_t)l*G3,      b_hh + (size_t)l*G3);
    }
    fc_sigmoid_kernel<<<BATCH/256, 256, 0, stream>>>(act, fc_w, fc_b, out);
}